// Round 3
// baseline (436.991 us; speedup 1.0000x reference)
//
#include <hip/hip_runtime.h>
#include <hip/hip_bf16.h>
#include <stdint.h>
#include <stddef.h>

// ---------- types ----------
typedef __bf16 bf16x8 __attribute__((ext_vector_type(8)));
typedef float  f32x4  __attribute__((ext_vector_type(4)));

#define BM 128
#define BN 128
#define BK 64

// ---------- helpers ----------
__device__ __forceinline__ float fp8e4m3_to_f32(uint32_t b) {
    // OCP e4m3fn: s eeee mmm, bias 7.
    uint32_t e = (b >> 3) & 15u, m = b & 7u;
    float mag;
    if (e == 0)
        mag = (float)m * (1.0f / 512.0f);            // subnormal: m * 2^-9
    else
        mag = __uint_as_float(((e + 120u) << 23) | (m << 20)); // (1+m/8)*2^(e-7)
    return (b & 0x80u) ? -mag : mag;
}

__device__ __forceinline__ unsigned short f32_to_bf16_bits(float f) {
    uint32_t x = __float_as_uint(f);
    uint32_t r = x + 0x7fffu + ((x >> 16) & 1u);   // RNE
    return (unsigned short)(r >> 16);
}

__device__ __forceinline__ void gload_lds16(const void* g, void* l) {
    // async global -> LDS, 16B per lane; LDS dest is wave-uniform base + lane*16
    __builtin_amdgcn_global_load_lds(
        (const __attribute__((address_space(1))) uint32_t*)g,
        (__attribute__((address_space(3))) uint32_t*)l,
        16, 0, 0);
}

// ---------- dtype detector (3-way) ----------
// mode 0: weight pushed as f32 holding fp8-representable values.
//         Signature: EVERY u32 has bits[19:0]==0 (e4m3 -> 3 mantissa bits).
//         bf16 or raw-fp8 streams fail this almost surely.
// mode 1: weight pushed as bf16. Signature: every 16-bit half has low
//         nibble == 0 (fp8 values have <=3 mantissa bits in bf16).
//         (f32 data also passes this, so f32 check runs FIRST.)
// mode 2: raw fp8 bytes (fails both).
__global__ void detect_kernel(const uint32_t* __restrict__ w,
                              uint32_t* __restrict__ flag) {
    __shared__ int sF, sB;
    if (threadIdx.x == 0) { sF = 1; sB = 1; }
    __syncthreads();
    int f32ok = 1, bf16ok = 1;
    #pragma unroll
    for (int i = 0; i < 16; ++i) {
        uint32_t u = w[threadIdx.x * 16 + i];
        if (u & 0x000FFFFFu) f32ok = 0;
        if (u & 0x000F000Fu) bf16ok = 0;
    }
    if (!f32ok)  atomicExch(&sF, 0);
    if (!bf16ok) atomicExch(&sB, 0);
    __syncthreads();
    if (threadIdx.x == 0)
        *flag = sF ? 0u : (sB ? 1u : 2u);
}

// ---------- pre-pass 1: x f32 -> bf16 ----------
__global__ void cvt_x_kernel(const float* __restrict__ x,
                             unsigned short* __restrict__ out, size_t n8) {
    size_t stride = (size_t)gridDim.x * blockDim.x;
    for (size_t i = (size_t)blockIdx.x * blockDim.x + threadIdx.x; i < n8; i += stride) {
        const float4* p = (const float4*)(x + i * 8);
        float4 a = p[0], b = p[1];
        union { uint4 v; unsigned short s[8]; } o;
        o.s[0] = f32_to_bf16_bits(a.x); o.s[1] = f32_to_bf16_bits(a.y);
        o.s[2] = f32_to_bf16_bits(a.z); o.s[3] = f32_to_bf16_bits(a.w);
        o.s[4] = f32_to_bf16_bits(b.x); o.s[5] = f32_to_bf16_bits(b.y);
        o.s[6] = f32_to_bf16_bits(b.z); o.s[7] = f32_to_bf16_bits(b.w);
        *(uint4*)(out + i * 8) = o.v;
    }
}

// ---------- pre-pass 2: weight (any mode) -> canonical bf16 ----------
__global__ void prep_w_kernel(const void* __restrict__ wsrc,
                              const uint32_t* __restrict__ flag,
                              unsigned short* __restrict__ out, size_t n8) {
    const uint32_t mode = *flag;
    size_t stride = (size_t)gridDim.x * blockDim.x;
    for (size_t i = (size_t)blockIdx.x * blockDim.x + threadIdx.x; i < n8; i += stride) {
        union { uint4 v; unsigned short s[8]; } o;
        if (mode == 0) {                      // f32 -> bf16 (values exact)
            const float4* p = (const float4*)((const float*)wsrc + i * 8);
            float4 a = p[0], b = p[1];
            o.s[0] = f32_to_bf16_bits(a.x); o.s[1] = f32_to_bf16_bits(a.y);
            o.s[2] = f32_to_bf16_bits(a.z); o.s[3] = f32_to_bf16_bits(a.w);
            o.s[4] = f32_to_bf16_bits(b.x); o.s[5] = f32_to_bf16_bits(b.y);
            o.s[6] = f32_to_bf16_bits(b.z); o.s[7] = f32_to_bf16_bits(b.w);
        } else if (mode == 1) {               // bf16 -> copy
            o.v = *(const uint4*)((const unsigned short*)wsrc + i * 8);
        } else {                              // raw fp8 -> decode (exact)
            union { uint2 v; uint8_t b[8]; } u;
            u.v = *(const uint2*)((const uint8_t*)wsrc + i * 8);
            #pragma unroll
            for (int j = 0; j < 8; ++j)
                o.s[j] = f32_to_bf16_bits(fp8e4m3_to_f32(u.b[j]));
        }
        *(uint4*)(out + i * 8) = o.v;
    }
}

// ---------- main GEMM: C[M,N] = (A[M,K] * W[N,K]^T) * inv + bias ----------
__global__ __launch_bounds__(256)
void gemm_bt_bias(const unsigned short* __restrict__ A,
                  const unsigned short* __restrict__ Bw,
                  const float* __restrict__ invp,
                  const float* __restrict__ bias,
                  float* __restrict__ C, int M, int N, int K) {
    __shared__ __attribute__((aligned(16))) unsigned short Als[BM * BK];
    __shared__ __attribute__((aligned(16))) unsigned short Bls[BN * BK];

    const float inv = *invp;

    const int nbn = N / BN;
    const int tm = blockIdx.x / nbn;
    const int tn = blockIdx.x % nbn;

    const int t = threadIdx.x;
    const int lane = t & 63;
    const int w = t >> 6;           // wave 0..3
    const int wr = w >> 1;          // wave row half (0..1)
    const int wc = w & 1;           // wave col half (0..1)
    const int laneQ = lane & 15;
    const int laneH = lane >> 4;

    const int r0 = t >> 3;          // 0..31
    const int c0 = (t & 7) * 8;     // bf16 col within BK

    f32x4 acc[4][4] = {};

    const int KT = K / BK;
    for (int kt = 0; kt < KT; ++kt) {
        #pragma unroll
        for (int i = 0; i < 4; ++i) {
            int r = i * 32 + r0;
            gload_lds16(A + (size_t)(tm * BM + r) * K + (size_t)kt * BK + c0,
                        &Als[r * BK + c0]);
        }
        #pragma unroll
        for (int i = 0; i < 4; ++i) {
            int r = i * 32 + r0;
            gload_lds16(Bw + (size_t)(tn * BN + r) * K + (size_t)kt * BK + c0,
                        &Bls[r * BK + c0]);
        }
        asm volatile("s_waitcnt vmcnt(0)" ::: "memory");
        __syncthreads();

        #pragma unroll
        for (int ks = 0; ks < 2; ++ks) {
            bf16x8 af[4], bfr[4];
            #pragma unroll
            for (int m = 0; m < 4; ++m)
                af[m] = *(const bf16x8*)&Als[(wr * 64 + m * 16 + laneQ) * BK + ks * 32 + laneH * 8];
            #pragma unroll
            for (int n = 0; n < 4; ++n)
                bfr[n] = *(const bf16x8*)&Bls[(wc * 64 + n * 16 + laneQ) * BK + ks * 32 + laneH * 8];
            #pragma unroll
            for (int m = 0; m < 4; ++m)
                #pragma unroll
                for (int n = 0; n < 4; ++n)
                    acc[m][n] = __builtin_amdgcn_mfma_f32_16x16x32_bf16(
                        af[m], bfr[n], acc[m][n], 0, 0, 0);
        }
        __syncthreads();
    }

    // epilogue: C/D layout col=lane&15, row=(lane>>4)*4+reg  [m89-verified]
    float bv[4];
    #pragma unroll
    for (int n = 0; n < 4; ++n)
        bv[n] = bias[tn * BN + wc * 64 + n * 16 + laneQ];

    #pragma unroll
    for (int m = 0; m < 4; ++m) {
        int rowb = tm * BM + wr * 64 + m * 16 + laneH * 4;
        #pragma unroll
        for (int j = 0; j < 4; ++j) {
            float* cp = C + (size_t)(rowb + j) * N + tn * BN + wc * 64;
            #pragma unroll
            for (int n = 0; n < 4; ++n)
                cp[n * 16 + laneQ] = acc[m][n][j] * inv + bv[n];
        }
    }
}

// ---------- fallback (insurance, mode-aware) ----------
__global__ void naive_kernel(const float* __restrict__ x,
                             const void* __restrict__ wsrc,
                             const uint32_t* flag,
                             const float* __restrict__ invp,
                             const float* __restrict__ bias,
                             float* __restrict__ out, int M, int N, int K) {
    const uint32_t mode = flag ? *flag : 0u;
    size_t idx = (size_t)blockIdx.x * blockDim.x + threadIdx.x;
    if (idx >= (size_t)M * N) return;
    int m = (int)(idx / N), n = (int)(idx % N);
    const float* xr = x + (size_t)m * K;
    float s = 0.f;
    if (mode == 0) {
        const float* wr = (const float*)wsrc + (size_t)n * K;
        for (int k = 0; k < K; ++k) s += xr[k] * wr[k];
    } else if (mode == 1) {
        const unsigned short* wr = (const unsigned short*)wsrc + (size_t)n * K;
        for (int k = 0; k < K; ++k)
            s += xr[k] * __uint_as_float(((uint32_t)wr[k]) << 16);
    } else {
        const uint8_t* wr = (const uint8_t*)wsrc + (size_t)n * K;
        for (int k = 0; k < K; ++k) s += xr[k] * fp8e4m3_to_f32(wr[k]);
    }
    out[idx] = s * (*invp) + bias[n];
}

extern "C" void kernel_launch(void* const* d_in, const int* in_sizes, int n_in,
                              void* d_out, int out_size, void* d_ws, size_t ws_size,
                              hipStream_t stream) {
    const float*    x    = (const float*)d_in[0];
    const void*     wsrc = d_in[1];
    const float*    inv  = (const float*)d_in[2];
    const float*    bias = (const float*)d_in[3];
    float*          out  = (float*)d_out;

    const int K = in_sizes[1] / in_sizes[3];   // D_IN  = 4096
    const int N = in_sizes[3];                 // D_OUT = 4096
    const int M = in_sizes[0] / K;             // B*S   = 8192

    const size_t needA = (size_t)M * K * sizeof(unsigned short);
    const size_t needB = (size_t)N * K * sizeof(unsigned short);

    if (ws_size < needA + needB + 256 || (M % BM) || (N % BN) || (K % BK)) {
        size_t total = (size_t)M * N;
        uint32_t* flag = (ws_size >= 256) ? (uint32_t*)d_ws : nullptr;
        if (flag) detect_kernel<<<1, 256, 0, stream>>>((const uint32_t*)wsrc, flag);
        naive_kernel<<<(unsigned)((total + 255) / 256), 256, 0, stream>>>(
            x, wsrc, flag, inv, bias, out, M, N, K);
        return;
    }

    uint32_t*       flag = (uint32_t*)d_ws;
    unsigned short* Abf  = (unsigned short*)((char*)d_ws + 256);
    unsigned short* Wbf  = (unsigned short*)((char*)d_ws + 256 + needA);

    detect_kernel<<<1, 256, 0, stream>>>((const uint32_t*)wsrc, flag);
    cvt_x_kernel<<<2048, 256, 0, stream>>>(x, Abf, (size_t)M * K / 8);
    prep_w_kernel<<<2048, 256, 0, stream>>>(wsrc, flag, Wbf, (size_t)N * K / 8);

    dim3 grid((M / BM) * (N / BN));
    gemm_bt_bias<<<grid, 256, 0, stream>>>(Abf, Wbf, inv, bias, out, M, N, K);
}

// Round 4
// 307.490 us; speedup vs baseline: 1.4212x; 1.4212x over previous
//
#include <hip/hip_runtime.h>
#include <hip/hip_bf16.h>
#include <stdint.h>
#include <stddef.h>

// ---------- types ----------
typedef __bf16 bf16x8 __attribute__((ext_vector_type(8)));
typedef float  f32x4  __attribute__((ext_vector_type(4)));

// ---------- helpers ----------
__device__ __forceinline__ float fp8e4m3_to_f32(uint32_t b) {
    uint32_t e = (b >> 3) & 15u, m = b & 7u;
    float mag;
    if (e == 0)
        mag = (float)m * (1.0f / 512.0f);
    else
        mag = __uint_as_float(((e + 120u) << 23) | (m << 20));
    return (b & 0x80u) ? -mag : mag;
}

__device__ __forceinline__ unsigned short f32_to_bf16_bits(float f) {
    uint32_t x = __float_as_uint(f);
    uint32_t r = x + 0x7fffu + ((x >> 16) & 1u);   // RNE
    return (unsigned short)(r >> 16);
}

__device__ __forceinline__ void gload_lds16(const void* g, void* l) {
    __builtin_amdgcn_global_load_lds(
        (const __attribute__((address_space(1))) uint32_t*)g,
        (__attribute__((address_space(3))) uint32_t*)l,
        16, 0, 0);
}

// ---------- dtype detector (3-way), validated round 3 (mode 0 = f32) ----------
__global__ void detect_kernel(const uint32_t* __restrict__ w,
                              uint32_t* __restrict__ flag) {
    __shared__ int sF, sB;
    if (threadIdx.x == 0) { sF = 1; sB = 1; }
    __syncthreads();
    int f32ok = 1, bf16ok = 1;
    #pragma unroll
    for (int i = 0; i < 16; ++i) {
        uint32_t u = w[threadIdx.x * 16 + i];
        if (u & 0x000FFFFFu) f32ok = 0;
        if (u & 0x000F000Fu) bf16ok = 0;
    }
    if (!f32ok)  atomicExch(&sF, 0);
    if (!bf16ok) atomicExch(&sB, 0);
    __syncthreads();
    if (threadIdx.x == 0)
        *flag = sF ? 0u : (sB ? 1u : 2u);
}

// ---------- pre-pass 1: x f32 -> bf16 ----------
__global__ void cvt_x_kernel(const float* __restrict__ x,
                             unsigned short* __restrict__ out, size_t n8) {
    size_t stride = (size_t)gridDim.x * blockDim.x;
    for (size_t i = (size_t)blockIdx.x * blockDim.x + threadIdx.x; i < n8; i += stride) {
        const float4* p = (const float4*)(x + i * 8);
        float4 a = p[0], b = p[1];
        union { uint4 v; unsigned short s[8]; } o;
        o.s[0] = f32_to_bf16_bits(a.x); o.s[1] = f32_to_bf16_bits(a.y);
        o.s[2] = f32_to_bf16_bits(a.z); o.s[3] = f32_to_bf16_bits(a.w);
        o.s[4] = f32_to_bf16_bits(b.x); o.s[5] = f32_to_bf16_bits(b.y);
        o.s[6] = f32_to_bf16_bits(b.z); o.s[7] = f32_to_bf16_bits(b.w);
        *(uint4*)(out + i * 8) = o.v;
    }
}

// ---------- pre-pass 2: weight (any mode) -> canonical bf16 ----------
__global__ void prep_w_kernel(const void* __restrict__ wsrc,
                              const uint32_t* __restrict__ flag,
                              unsigned short* __restrict__ out, size_t n8) {
    const uint32_t mode = *flag;
    size_t stride = (size_t)gridDim.x * blockDim.x;
    for (size_t i = (size_t)blockIdx.x * blockDim.x + threadIdx.x; i < n8; i += stride) {
        union { uint4 v; unsigned short s[8]; } o;
        if (mode == 0) {
            const float4* p = (const float4*)((const float*)wsrc + i * 8);
            float4 a = p[0], b = p[1];
            o.s[0] = f32_to_bf16_bits(a.x); o.s[1] = f32_to_bf16_bits(a.y);
            o.s[2] = f32_to_bf16_bits(a.z); o.s[3] = f32_to_bf16_bits(a.w);
            o.s[4] = f32_to_bf16_bits(b.x); o.s[5] = f32_to_bf16_bits(b.y);
            o.s[6] = f32_to_bf16_bits(b.z); o.s[7] = f32_to_bf16_bits(b.w);
        } else if (mode == 1) {
            o.v = *(const uint4*)((const unsigned short*)wsrc + i * 8);
        } else {
            union { uint2 v; uint8_t b[8]; } u;
            u.v = *(const uint2*)((const uint8_t*)wsrc + i * 8);
            #pragma unroll
            for (int j = 0; j < 8; ++j)
                o.s[j] = f32_to_bf16_bits(fp8e4m3_to_f32(u.b[j]));
        }
        *(uint4*)(out + i * 8) = o.v;
    }
}

// ================= 256x256 8-phase GEMM (m201 template, plain HIP) ==========
// C[M,N] = (A[M,K] * W[N,K]^T) * inv + bias, bf16 in, f32 out.
// 8 waves (2M x 4N), per-wave 128x64 output, BK=64.
// LDS: 2 bufs x {A,B} x [256][64] bf16 = 128 KiB, double-buffered.
// T2: read-side XOR swizzle colbyte ^= (row&7)<<4; stage uses inverse-swizzled
//     GLOBAL source with linear global_load_lds dest (rule 21).
// T3/T4: 4 phases/K-tile, stage kt+2 during P3 (B) / P4 (A) into buf[kt&1]
//     whose regions are provably dead (last read >=1 barrier earlier);
//     vmcnt(8) once per K-tile (never 0 in steady state).
// T5: setprio(1) around each 16-MFMA cluster.

#define GBM 256
#define GBN 256
#define GBK 64

#define STAGE_(gp, row0, ldsw, kb) do {                                        \
    _Pragma("unroll")                                                          \
    for (int j = 0; j < 4; ++j)                                                \
        gload_lds16((gp) + ((size_t)((row0) + j*64 + wid*8 + lrow)) * KB2 + (kb), \
                    (ldsw) + (size_t)(j*64 + wid*8) * 128 + lane * 16);        \
} while (0)

#define LDA_(qm) do {                                                          \
    _Pragma("unroll") for (int m = 0; m < 4; ++m)                              \
    _Pragma("unroll") for (int ks = 0; ks < 2; ++ks)                           \
        Af[m][ks] = *(const bf16x8*)(ldsA                                      \
            + (size_t)(wm*128 + ((qm)*4+m)*16 + laneQ) * 128                   \
            + ((ks*64 + laneH*16) ^ xorv));                                    \
} while (0)

#define LDB_(qn, Bf) do {                                                      \
    _Pragma("unroll") for (int n = 0; n < 2; ++n)                              \
    _Pragma("unroll") for (int ks = 0; ks < 2; ++ks)                           \
        Bf[n][ks] = *(const bf16x8*)(ldsB                                      \
            + (size_t)(wn*64 + ((qn)*2+n)*16 + laneQ) * 128                    \
            + ((ks*64 + laneH*16) ^ xorv));                                    \
} while (0)

#define MFMA_(qm, qn, Bf) do {                                                 \
    _Pragma("unroll") for (int m = 0; m < 4; ++m)                              \
    _Pragma("unroll") for (int n = 0; n < 2; ++n)                              \
    _Pragma("unroll") for (int ks = 0; ks < 2; ++ks)                           \
        acc[(qm)*4+m][(qn)*2+n] = __builtin_amdgcn_mfma_f32_16x16x32_bf16(     \
            Af[m][ks], Bf[n][ks], acc[(qm)*4+m][(qn)*2+n], 0, 0, 0);           \
} while (0)

#define PH_IN() do {                                                           \
    __builtin_amdgcn_s_barrier();                                              \
    asm volatile("s_waitcnt lgkmcnt(0)" ::: "memory");                         \
    __builtin_amdgcn_sched_barrier(0);                                         \
    __builtin_amdgcn_s_setprio(1);                                             \
} while (0)

#define PH_OUT() do {                                                          \
    __builtin_amdgcn_s_setprio(0);                                             \
    __builtin_amdgcn_s_barrier();                                              \
} while (0)

__global__ __launch_bounds__(512, 2)
void gemm256_8ph(const unsigned short* __restrict__ A,
                 const unsigned short* __restrict__ Bw,
                 const float* __restrict__ invp,
                 const float* __restrict__ bias,
                 float* __restrict__ C, int M, int N, int K) {
    __shared__ unsigned short lds[2][2][GBM * GBK];   // 128 KiB

    const size_t KB2 = (size_t)K * 2;
    const int KT = K / GBK;

    // bijective XCD swizzle (grid % 8 == 0 guaranteed by dispatch guard)
    const int nwg = gridDim.x;
    const int b   = blockIdx.x;
    const int wg  = (b & 7) * (nwg >> 3) + (b >> 3);
    const int MT  = M / GBM;
    const int tm  = wg % MT;        // M-fast: each XCD chunk keeps 2 B-panels L2-hot
    const int tn  = wg / MT;

    const int t     = threadIdx.x;
    const int lane  = t & 63;
    const int wid   = t >> 6;       // 0..7
    const int wm    = wid >> 2;     // 0..1
    const int wn    = wid & 3;      // 0..3
    const int laneQ = lane & 15;
    const int laneH = lane >> 4;
    const int xorv  = (laneQ & 7) << 4;     // T2 read swizzle
    const int lrow  = lane >> 3;            // staging: row-within-8
    // inverse-swizzled source 16B block (same involution as read)
    const int lcb   = (lane & 7) ^ lrow;

    const uint8_t* Ag = (const uint8_t*)A;
    const uint8_t* Bg = (const uint8_t*)Bw;
    const size_t arow0 = (size_t)tm * GBM;
    const size_t brow0 = (size_t)tn * GBN;
    const size_t kbL = (size_t)lcb * 16;

    f32x4 acc[8][4] = {};
    bf16x8 Af[4][2], B0[2][2], B1[2][2];

    // ---- prologue: stage tiles 0 and 1 (KT >= 2 guaranteed) ----
    STAGE_(Bg, brow0, (uint8_t*)&lds[0][1][0], kbL);
    STAGE_(Ag, arow0, (uint8_t*)&lds[0][0][0], kbL);
    STAGE_(Bg, brow0, (uint8_t*)&lds[1][1][0], (size_t)128 + kbL);
    STAGE_(Ag, arow0, (uint8_t*)&lds[1][0][0], (size_t)128 + kbL);
    asm volatile("s_waitcnt vmcnt(8)" ::: "memory");   // tile 0 landed; tile 1 in flight
    __builtin_amdgcn_s_barrier();

    for (int kt = 0; kt < KT; ++kt) {
        const int c = kt & 1;
        const uint8_t* ldsA = (const uint8_t*)&lds[c][0][0];
        const uint8_t* ldsB = (const uint8_t*)&lds[c][1][0];
        uint8_t* ldsAw = (uint8_t*)&lds[c][0][0];
        uint8_t* ldsBw = (uint8_t*)&lds[c][1][0];
        const bool more = (kt + 2) < KT;
        const size_t kb2 = (size_t)(kt + 2) * 128 + kbL;

        // ---- P1: A(qm0) + B(qn0) reads; MFMA quadrant (0,0) ----
        LDA_(0);
        LDB_(0, B0);
        PH_IN();  MFMA_(0, 0, B0);  PH_OUT();

        // ---- P2: B(qn1) reads; MFMA (0,1) ----
        LDB_(1, B1);
        PH_IN();  MFMA_(0, 1, B1);  PH_OUT();

        // ---- P3: A(qm1) reads; stage B(kt+2) (B region dead since P2); MFMA (1,1) ----
        LDA_(1);
        if (more) STAGE_(Bg, brow0, ldsBw, kb2);
        PH_IN();  MFMA_(1, 1, B1);  PH_OUT();

        // ---- P4: stage A(kt+2) (A region dead since P3); MFMA (1,0) from regs ----
        if (more) STAGE_(Ag, arow0, ldsAw, kb2);
        __builtin_amdgcn_s_barrier();
        __builtin_amdgcn_sched_barrier(0);
        __builtin_amdgcn_s_setprio(1);
        MFMA_(1, 0, B0);
        __builtin_amdgcn_s_setprio(0);
        if (more) asm volatile("s_waitcnt vmcnt(8)" ::: "memory"); // next tile landed, kt+2 in flight
        else      asm volatile("s_waitcnt vmcnt(0)" ::: "memory"); // epilogue drain
        __builtin_amdgcn_s_barrier();
    }

    // ---- epilogue: C/D layout col=laneQ, row=laneH*4+reg [m89-verified] ----
    const float inv = *invp;
    float bv[4];
    #pragma unroll
    for (int n = 0; n < 4; ++n)
        bv[n] = bias[tn * GBN + wn * 64 + n * 16 + laneQ];

    #pragma unroll
    for (int m = 0; m < 8; ++m) {
        int rowb = tm * GBM + wm * 128 + m * 16 + laneH * 4;
        #pragma unroll
        for (int j = 0; j < 4; ++j) {
            float* cp = C + (size_t)(rowb + j) * N + tn * GBN + wn * 64;
            #pragma unroll
            for (int n = 0; n < 4; ++n)
                cp[n * 16 + laneQ] = acc[m][n][j] * inv + bv[n];
        }
    }
}

// ---------- fallback (insurance, mode-aware) ----------
__global__ void naive_kernel(const float* __restrict__ x,
                             const void* __restrict__ wsrc,
                             const uint32_t* flag,
                             const float* __restrict__ invp,
                             const float* __restrict__ bias,
                             float* __restrict__ out, int M, int N, int K) {
    const uint32_t mode = flag ? *flag : 0u;
    size_t idx = (size_t)blockIdx.x * blockDim.x + threadIdx.x;
    if (idx >= (size_t)M * N) return;
    int m = (int)(idx / N), n = (int)(idx % N);
    const float* xr = x + (size_t)m * K;
    float s = 0.f;
    if (mode == 0) {
        const float* wr = (const float*)wsrc + (size_t)n * K;
        for (int k = 0; k < K; ++k) s += xr[k] * wr[k];
    } else if (mode == 1) {
        const unsigned short* wr = (const unsigned short*)wsrc + (size_t)n * K;
        for (int k = 0; k < K; ++k)
            s += xr[k] * __uint_as_float(((uint32_t)wr[k]) << 16);
    } else {
        const uint8_t* wr = (const uint8_t*)wsrc + (size_t)n * K;
        for (int k = 0; k < K; ++k) s += xr[k] * fp8e4m3_to_f32(wr[k]);
    }
    out[idx] = s * (*invp) + bias[n];
}

extern "C" void kernel_launch(void* const* d_in, const int* in_sizes, int n_in,
                              void* d_out, int out_size, void* d_ws, size_t ws_size,
                              hipStream_t stream) {
    const float*    x    = (const float*)d_in[0];
    const void*     wsrc = d_in[1];
    const float*    inv  = (const float*)d_in[2];
    const float*    bias = (const float*)d_in[3];
    float*          out  = (float*)d_out;

    const int K = in_sizes[1] / in_sizes[3];   // D_IN  = 4096
    const int N = in_sizes[3];                 // D_OUT = 4096
    const int M = in_sizes[0] / K;             // B*S   = 8192

    const size_t needA = (size_t)M * K * sizeof(unsigned short);
    const size_t needB = (size_t)N * K * sizeof(unsigned short);

    const bool shape_ok = (M % GBM) == 0 && (N % GBN) == 0 && (K % GBK) == 0 &&
                          (K / GBK) >= 2 &&
                          (((M / GBM) * (N / GBN)) % 8) == 0;

    if (ws_size < needA + needB + 256 || !shape_ok) {
        size_t total = (size_t)M * N;
        uint32_t* flag = (ws_size >= 256) ? (uint32_t*)d_ws : nullptr;
        if (flag) detect_kernel<<<1, 256, 0, stream>>>((const uint32_t*)wsrc, flag);
        naive_kernel<<<(unsigned)((total + 255) / 256), 256, 0, stream>>>(
            x, wsrc, flag, inv, bias, out, M, N, K);
        return;
    }

    uint32_t*       flag = (uint32_t*)d_ws;
    unsigned short* Abf  = (unsigned short*)((char*)d_ws + 256);
    unsigned short* Wbf  = (unsigned short*)((char*)d_ws + 256 + needA);

    detect_kernel<<<1, 256, 0, stream>>>((const uint32_t*)wsrc, flag);
    cvt_x_kernel<<<2048, 256, 0, stream>>>(x, Abf, (size_t)M * K / 8);
    prep_w_kernel<<<2048, 256, 0, stream>>>(wsrc, flag, Wbf, (size_t)N * K / 8);

    dim3 grid((M / GBM) * (N / GBN));
    gemm256_8ph<<<grid, 512, 0, stream>>>(Abf, Wbf, inv, bias, out, M, N, K);
}

// Round 5
// 301.238 us; speedup vs baseline: 1.4506x; 1.0208x over previous
//
#include <hip/hip_runtime.h>
#include <hip/hip_bf16.h>
#include <stdint.h>
#include <stddef.h>

// ---------- types ----------
typedef __bf16 bf16x8 __attribute__((ext_vector_type(8)));
typedef float  f32x4  __attribute__((ext_vector_type(4)));

// ---------- helpers ----------
__device__ __forceinline__ float fp8e4m3_to_f32(uint32_t b) {
    uint32_t e = (b >> 3) & 15u, m = b & 7u;
    float mag;
    if (e == 0)
        mag = (float)m * (1.0f / 512.0f);
    else
        mag = __uint_as_float(((e + 120u) << 23) | (m << 20));
    return (b & 0x80u) ? -mag : mag;
}

__device__ __forceinline__ unsigned short f32_to_bf16_bits(float f) {
    uint32_t x = __float_as_uint(f);
    uint32_t r = x + 0x7fffu + ((x >> 16) & 1u);   // RNE
    return (unsigned short)(r >> 16);
}

__device__ __forceinline__ void gload_lds16(const void* g, void* l) {
    __builtin_amdgcn_global_load_lds(
        (const __attribute__((address_space(1))) uint32_t*)g,
        (__attribute__((address_space(3))) uint32_t*)l,
        16, 0, 0);
}

// ---------- dtype detector (3-way), validated round 3 (mode 0 = f32) ----------
__global__ void detect_kernel(const uint32_t* __restrict__ w,
                              uint32_t* __restrict__ flag) {
    __shared__ int sF, sB;
    if (threadIdx.x == 0) { sF = 1; sB = 1; }
    __syncthreads();
    int f32ok = 1, bf16ok = 1;
    #pragma unroll
    for (int i = 0; i < 16; ++i) {
        uint32_t u = w[threadIdx.x * 16 + i];
        if (u & 0x000FFFFFu) f32ok = 0;
        if (u & 0x000F000Fu) bf16ok = 0;
    }
    if (!f32ok)  atomicExch(&sF, 0);
    if (!bf16ok) atomicExch(&sB, 0);
    __syncthreads();
    if (threadIdx.x == 0)
        *flag = sF ? 0u : (sB ? 1u : 2u);
}

// ---------- pre-pass 1: x f32 -> bf16 ----------
__global__ void cvt_x_kernel(const float* __restrict__ x,
                             unsigned short* __restrict__ out, size_t n8) {
    size_t stride = (size_t)gridDim.x * blockDim.x;
    for (size_t i = (size_t)blockIdx.x * blockDim.x + threadIdx.x; i < n8; i += stride) {
        const float4* p = (const float4*)(x + i * 8);
        float4 a = p[0], b = p[1];
        union { uint4 v; unsigned short s[8]; } o;
        o.s[0] = f32_to_bf16_bits(a.x); o.s[1] = f32_to_bf16_bits(a.y);
        o.s[2] = f32_to_bf16_bits(a.z); o.s[3] = f32_to_bf16_bits(a.w);
        o.s[4] = f32_to_bf16_bits(b.x); o.s[5] = f32_to_bf16_bits(b.y);
        o.s[6] = f32_to_bf16_bits(b.z); o.s[7] = f32_to_bf16_bits(b.w);
        *(uint4*)(out + i * 8) = o.v;
    }
}

// ---------- pre-pass 2: weight (any mode) -> canonical bf16 ----------
__global__ void prep_w_kernel(const void* __restrict__ wsrc,
                              const uint32_t* __restrict__ flag,
                              unsigned short* __restrict__ out, size_t n8) {
    const uint32_t mode = *flag;
    size_t stride = (size_t)gridDim.x * blockDim.x;
    for (size_t i = (size_t)blockIdx.x * blockDim.x + threadIdx.x; i < n8; i += stride) {
        union { uint4 v; unsigned short s[8]; } o;
        if (mode == 0) {
            const float4* p = (const float4*)((const float*)wsrc + i * 8);
            float4 a = p[0], b = p[1];
            o.s[0] = f32_to_bf16_bits(a.x); o.s[1] = f32_to_bf16_bits(a.y);
            o.s[2] = f32_to_bf16_bits(a.z); o.s[3] = f32_to_bf16_bits(a.w);
            o.s[4] = f32_to_bf16_bits(b.x); o.s[5] = f32_to_bf16_bits(b.y);
            o.s[6] = f32_to_bf16_bits(b.z); o.s[7] = f32_to_bf16_bits(b.w);
        } else if (mode == 1) {
            o.v = *(const uint4*)((const unsigned short*)wsrc + i * 8);
        } else {
            union { uint2 v; uint8_t b[8]; } u;
            u.v = *(const uint2*)((const uint8_t*)wsrc + i * 8);
            #pragma unroll
            for (int j = 0; j < 8; ++j)
                o.s[j] = f32_to_bf16_bits(fp8e4m3_to_f32(u.b[j]));
        }
        *(uint4*)(out + i * 8) = o.v;
    }
}

// ================= 256x256 8-phase GEMM (m201 template, plain HIP) ==========
// Round-5 delta vs round-4: PH_IN softened to {barrier; setprio(1)} — no
// asm lgkmcnt(0) / sched_barrier(0) (rule 18 applies only to inline-asm
// ds_reads; plain loads get compiler fine-grained lgkm interleave, m97).
// P4's redundant pre-MFMA barrier removed (no ds_reads in P4; A-stage WAR
// hazard already closed by P3's closing barrier).
// Hazards kept closed: B-stage > P2-out bar, A-stage > P3-out bar, buffer
// readiness > per-wave vmcnt(8) + P4-end bar; vmcnt asm "memory" clobber
// pins cross-phase load/stage ordering.

#define GBM 256
#define GBN 256
#define GBK 64

#define STAGE_(gp, row0, ldsw, kb) do {                                        \
    _Pragma("unroll")                                                          \
    for (int j = 0; j < 4; ++j)                                                \
        gload_lds16((gp) + ((size_t)((row0) + j*64 + wid*8 + lrow)) * KB2 + (kb), \
                    (ldsw) + (size_t)(j*64 + wid*8) * 128 + lane * 16);        \
} while (0)

#define LDA_(qm) do {                                                          \
    _Pragma("unroll") for (int m = 0; m < 4; ++m)                              \
    _Pragma("unroll") for (int ks = 0; ks < 2; ++ks)                           \
        Af[m][ks] = *(const bf16x8*)(ldsA                                      \
            + (size_t)(wm*128 + ((qm)*4+m)*16 + laneQ) * 128                   \
            + ((ks*64 + laneH*16) ^ xorv));                                    \
} while (0)

#define LDB_(qn, Bf) do {                                                      \
    _Pragma("unroll") for (int n = 0; n < 2; ++n)                              \
    _Pragma("unroll") for (int ks = 0; ks < 2; ++ks)                           \
        Bf[n][ks] = *(const bf16x8*)(ldsB                                      \
            + (size_t)(wn*64 + ((qn)*2+n)*16 + laneQ) * 128                    \
            + ((ks*64 + laneH*16) ^ xorv));                                    \
} while (0)

#define MFMA_(qm, qn, Bf) do {                                                 \
    _Pragma("unroll") for (int m = 0; m < 4; ++m)                              \
    _Pragma("unroll") for (int n = 0; n < 2; ++n)                              \
    _Pragma("unroll") for (int ks = 0; ks < 2; ++ks)                           \
        acc[(qm)*4+m][(qn)*2+n] = __builtin_amdgcn_mfma_f32_16x16x32_bf16(     \
            Af[m][ks], Bf[n][ks], acc[(qm)*4+m][(qn)*2+n], 0, 0, 0);           \
} while (0)

#define PH_IN() do {                                                           \
    __builtin_amdgcn_s_barrier();                                              \
    __builtin_amdgcn_s_setprio(1);                                             \
} while (0)

#define PH_OUT() do {                                                          \
    __builtin_amdgcn_s_setprio(0);                                             \
    __builtin_amdgcn_s_barrier();                                              \
} while (0)

__global__ __launch_bounds__(512, 2)
void gemm256_8ph(const unsigned short* __restrict__ A,
                 const unsigned short* __restrict__ Bw,
                 const float* __restrict__ invp,
                 const float* __restrict__ bias,
                 float* __restrict__ C, int M, int N, int K) {
    __shared__ unsigned short lds[2][2][GBM * GBK];   // 128 KiB

    const size_t KB2 = (size_t)K * 2;
    const int KT = K / GBK;

    // bijective XCD swizzle (grid % 8 == 0 guaranteed by dispatch guard)
    const int nwg = gridDim.x;
    const int b   = blockIdx.x;
    const int wg  = (b & 7) * (nwg >> 3) + (b >> 3);
    const int MT  = M / GBM;
    const int tm  = wg % MT;
    const int tn  = wg / MT;

    const int t     = threadIdx.x;
    const int lane  = t & 63;
    const int wid   = t >> 6;       // 0..7
    const int wm    = wid >> 2;     // 0..1
    const int wn    = wid & 3;      // 0..3
    const int laneQ = lane & 15;
    const int laneH = lane >> 4;
    const int xorv  = (laneQ & 7) << 4;     // T2 read swizzle
    const int lrow  = lane >> 3;            // staging: row-within-8
    const int lcb   = (lane & 7) ^ lrow;    // inverse-swizzled source block

    const uint8_t* Ag = (const uint8_t*)A;
    const uint8_t* Bg = (const uint8_t*)Bw;
    const size_t arow0 = (size_t)tm * GBM;
    const size_t brow0 = (size_t)tn * GBN;
    const size_t kbL = (size_t)lcb * 16;

    f32x4 acc[8][4] = {};
    bf16x8 Af[4][2], B0[2][2], B1[2][2];

    // ---- prologue: stage tiles 0 and 1 (KT >= 2 guaranteed) ----
    STAGE_(Bg, brow0, (uint8_t*)&lds[0][1][0], kbL);
    STAGE_(Ag, arow0, (uint8_t*)&lds[0][0][0], kbL);
    STAGE_(Bg, brow0, (uint8_t*)&lds[1][1][0], (size_t)128 + kbL);
    STAGE_(Ag, arow0, (uint8_t*)&lds[1][0][0], (size_t)128 + kbL);
    asm volatile("s_waitcnt vmcnt(8)" ::: "memory");   // tile 0 landed
    __builtin_amdgcn_s_barrier();

    for (int kt = 0; kt < KT; ++kt) {
        const int c = kt & 1;
        const uint8_t* ldsA = (const uint8_t*)&lds[c][0][0];
        const uint8_t* ldsB = (const uint8_t*)&lds[c][1][0];
        uint8_t* ldsAw = (uint8_t*)&lds[c][0][0];
        uint8_t* ldsBw = (uint8_t*)&lds[c][1][0];
        const bool more = (kt + 2) < KT;
        const size_t kb2 = (size_t)(kt + 2) * 128 + kbL;

        // ---- P1: A(qm0)+B(qn0) reads; MFMA (0,0) ----
        LDA_(0);
        LDB_(0, B0);
        PH_IN();  MFMA_(0, 0, B0);  PH_OUT();

        // ---- P2: B(qn1) reads; MFMA (0,1) ----
        LDB_(1, B1);
        PH_IN();  MFMA_(0, 1, B1);  PH_OUT();

        // ---- P3: A(qm1) reads; stage B(kt+2) (B dead since P2-out); MFMA (1,1) ----
        LDA_(1);
        if (more) STAGE_(Bg, brow0, ldsBw, kb2);
        PH_IN();  MFMA_(1, 1, B1);  PH_OUT();

        // ---- P4: stage A(kt+2) (A dead since P3-out); MFMA (1,0) from regs ----
        if (more) STAGE_(Ag, arow0, ldsAw, kb2);
        __builtin_amdgcn_s_setprio(1);
        MFMA_(1, 0, B0);
        __builtin_amdgcn_s_setprio(0);
        if (more) asm volatile("s_waitcnt vmcnt(8)" ::: "memory"); // kt+1 landed
        else      asm volatile("s_waitcnt vmcnt(0)" ::: "memory"); // drain
        __builtin_amdgcn_s_barrier();
    }

    // ---- epilogue: C/D layout col=laneQ, row=laneH*4+reg [m89-verified] ----
    const float inv = *invp;
    float bv[4];
    #pragma unroll
    for (int n = 0; n < 4; ++n)
        bv[n] = bias[tn * GBN + wn * 64 + n * 16 + laneQ];

    #pragma unroll
    for (int m = 0; m < 8; ++m) {
        int rowb = tm * GBM + wm * 128 + m * 16 + laneH * 4;
        #pragma unroll
        for (int j = 0; j < 4; ++j) {
            float* cp = C + (size_t)(rowb + j) * N + tn * GBN + wn * 64;
            #pragma unroll
            for (int n = 0; n < 4; ++n)
                cp[n * 16 + laneQ] = acc[m][n][j] * inv + bv[n];
        }
    }
}

// ---------- fallback (insurance, mode-aware) ----------
__global__ void naive_kernel(const float* __restrict__ x,
                             const void* __restrict__ wsrc,
                             const uint32_t* flag,
                             const float* __restrict__ invp,
                             const float* __restrict__ bias,
                             float* __restrict__ out, int M, int N, int K) {
    const uint32_t mode = flag ? *flag : 0u;
    size_t idx = (size_t)blockIdx.x * blockDim.x + threadIdx.x;
    if (idx >= (size_t)M * N) return;
    int m = (int)(idx / N), n = (int)(idx % N);
    const float* xr = x + (size_t)m * K;
    float s = 0.f;
    if (mode == 0) {
        const float* wr = (const float*)wsrc + (size_t)n * K;
        for (int k = 0; k < K; ++k) s += xr[k] * wr[k];
    } else if (mode == 1) {
        const unsigned short* wr = (const unsigned short*)wsrc + (size_t)n * K;
        for (int k = 0; k < K; ++k)
            s += xr[k] * __uint_as_float(((uint32_t)wr[k]) << 16);
    } else {
        const uint8_t* wr = (const uint8_t*)wsrc + (size_t)n * K;
        for (int k = 0; k < K; ++k) s += xr[k] * fp8e4m3_to_f32(wr[k]);
    }
    out[idx] = s * (*invp) + bias[n];
}

extern "C" void kernel_launch(void* const* d_in, const int* in_sizes, int n_in,
                              void* d_out, int out_size, void* d_ws, size_t ws_size,
                              hipStream_t stream) {
    const float*    x    = (const float*)d_in[0];
    const void*     wsrc = d_in[1];
    const float*    inv  = (const float*)d_in[2];
    const float*    bias = (const float*)d_in[3];
    float*          out  = (float*)d_out;

    const int K = in_sizes[1] / in_sizes[3];   // D_IN  = 4096
    const int N = in_sizes[3];                 // D_OUT = 4096
    const int M = in_sizes[0] / K;             // B*S   = 8192

    const size_t needA = (size_t)M * K * sizeof(unsigned short);
    const size_t needB = (size_t)N * K * sizeof(unsigned short);

    const bool shape_ok = (M % GBM) == 0 && (N % GBN) == 0 && (K % GBK) == 0 &&
                          (K / GBK) >= 2 &&
                          (((M / GBM) * (N / GBN)) % 8) == 0;

    if (ws_size < needA + needB + 256 || !shape_ok) {
        size_t total = (size_t)M * N;
        uint32_t* flag = (ws_size >= 256) ? (uint32_t*)d_ws : nullptr;
        if (flag) detect_kernel<<<1, 256, 0, stream>>>((const uint32_t*)wsrc, flag);
        naive_kernel<<<(unsigned)((total + 255) / 256), 256, 0, stream>>>(
            x, wsrc, flag, inv, bias, out, M, N, K);
        return;
    }

    uint32_t*       flag = (uint32_t*)d_ws;
    unsigned short* Abf  = (unsigned short*)((char*)d_ws + 256);
    unsigned short* Wbf  = (unsigned short*)((char*)d_ws + 256 + needA);

    detect_kernel<<<1, 256, 0, stream>>>((const uint32_t*)wsrc, flag);
    cvt_x_kernel<<<2048, 256, 0, stream>>>(x, Abf, (size_t)M * K / 8);
    prep_w_kernel<<<2048, 256, 0, stream>>>(wsrc, flag, Wbf, (size_t)N * K / 8);

    dim3 grid((M / GBM) * (N / GBN));
    gemm256_8ph<<<grid, 512, 0, stream>>>(Abf, Wbf, inv, bias, out, M, N, K);
}

// Round 6
// 300.409 us; speedup vs baseline: 1.4547x; 1.0028x over previous
//
#include <hip/hip_runtime.h>
#include <hip/hip_bf16.h>
#include <stdint.h>
#include <stddef.h>

// ---------- types ----------
typedef __bf16 bf16x8 __attribute__((ext_vector_type(8)));
typedef float  f32x4  __attribute__((ext_vector_type(4)));

// ---------- helpers ----------
__device__ __forceinline__ float fp8e4m3_to_f32(uint32_t b) {
    uint32_t e = (b >> 3) & 15u, m = b & 7u;
    float mag;
    if (e == 0)
        mag = (float)m * (1.0f / 512.0f);
    else
        mag = __uint_as_float(((e + 120u) << 23) | (m << 20));
    return (b & 0x80u) ? -mag : mag;
}

__device__ __forceinline__ unsigned short f32_to_bf16_bits(float f) {
    uint32_t x = __float_as_uint(f);
    uint32_t r = x + 0x7fffu + ((x >> 16) & 1u);   // RNE
    return (unsigned short)(r >> 16);
}

__device__ __forceinline__ void gload_lds16(const void* g, void* l) {
    __builtin_amdgcn_global_load_lds(
        (const __attribute__((address_space(1))) uint32_t*)g,
        (__attribute__((address_space(3))) uint32_t*)l,
        16, 0, 0);
}

// ---------- dtype detector (3-way), validated round 3 (mode 0 = f32) ----------
__global__ void detect_kernel(const uint32_t* __restrict__ w,
                              uint32_t* __restrict__ flag) {
    __shared__ int sF, sB;
    if (threadIdx.x == 0) { sF = 1; sB = 1; }
    __syncthreads();
    int f32ok = 1, bf16ok = 1;
    #pragma unroll
    for (int i = 0; i < 16; ++i) {
        uint32_t u = w[threadIdx.x * 16 + i];
        if (u & 0x000FFFFFu) f32ok = 0;
        if (u & 0x000F000Fu) bf16ok = 0;
    }
    if (!f32ok)  atomicExch(&sF, 0);
    if (!bf16ok) atomicExch(&sB, 0);
    __syncthreads();
    if (threadIdx.x == 0)
        *flag = sF ? 0u : (sB ? 1u : 2u);
}

// ---------- pre-pass 1: x f32 -> bf16 ----------
__global__ void cvt_x_kernel(const float* __restrict__ x,
                             unsigned short* __restrict__ out, size_t n8) {
    size_t stride = (size_t)gridDim.x * blockDim.x;
    for (size_t i = (size_t)blockIdx.x * blockDim.x + threadIdx.x; i < n8; i += stride) {
        const float4* p = (const float4*)(x + i * 8);
        float4 a = p[0], b = p[1];
        union { uint4 v; unsigned short s[8]; } o;
        o.s[0] = f32_to_bf16_bits(a.x); o.s[1] = f32_to_bf16_bits(a.y);
        o.s[2] = f32_to_bf16_bits(a.z); o.s[3] = f32_to_bf16_bits(a.w);
        o.s[4] = f32_to_bf16_bits(b.x); o.s[5] = f32_to_bf16_bits(b.y);
        o.s[6] = f32_to_bf16_bits(b.z); o.s[7] = f32_to_bf16_bits(b.w);
        *(uint4*)(out + i * 8) = o.v;
    }
}

// ---------- pre-pass 2: weight (any mode) -> canonical bf16 ----------
__global__ void prep_w_kernel(const void* __restrict__ wsrc,
                              const uint32_t* __restrict__ flag,
                              unsigned short* __restrict__ out, size_t n8) {
    const uint32_t mode = *flag;
    size_t stride = (size_t)gridDim.x * blockDim.x;
    for (size_t i = (size_t)blockIdx.x * blockDim.x + threadIdx.x; i < n8; i += stride) {
        union { uint4 v; unsigned short s[8]; } o;
        if (mode == 0) {
            const float4* p = (const float4*)((const float*)wsrc + i * 8);
            float4 a = p[0], b = p[1];
            o.s[0] = f32_to_bf16_bits(a.x); o.s[1] = f32_to_bf16_bits(a.y);
            o.s[2] = f32_to_bf16_bits(a.z); o.s[3] = f32_to_bf16_bits(a.w);
            o.s[4] = f32_to_bf16_bits(b.x); o.s[5] = f32_to_bf16_bits(b.y);
            o.s[6] = f32_to_bf16_bits(b.z); o.s[7] = f32_to_bf16_bits(b.w);
        } else if (mode == 1) {
            o.v = *(const uint4*)((const unsigned short*)wsrc + i * 8);
        } else {
            union { uint2 v; uint8_t b[8]; } u;
            u.v = *(const uint2*)((const uint8_t*)wsrc + i * 8);
            #pragma unroll
            for (int j = 0; j < 8; ++j)
                o.s[j] = f32_to_bf16_bits(fp8e4m3_to_f32(u.b[j]));
        }
        *(uint4*)(out + i * 8) = o.v;
    }
}

// ================= 256x256 8-phase GEMM (m201 template, plain HIP) ==========
// Round-6 delta vs round-5 (schedule UNCHANGED): addressing micro-opt.
// All LDS read addresses are precomputed 32-bit per-thread offsets; the
// m/n/qm/qn/ks unroll indices become compile-time ds_read offset:CONST
// immediates (A <= 14336, B <= 6144, fit 16-bit). Global staging uses one
// base pointer per tensor + constant j-strides. Goal: kill the ~250
// VALU/K-tile address rematerialization seen as VALUBusy 19.7%.

#define GBM 256
#define GBN 256
#define GBK 64

#define PH_IN() do {                                                           \
    __builtin_amdgcn_s_barrier();                                              \
    __builtin_amdgcn_s_setprio(1);                                             \
} while (0)

#define PH_OUT() do {                                                          \
    __builtin_amdgcn_s_setprio(0);                                             \
    __builtin_amdgcn_s_barrier();                                              \
} while (0)

// fragment reads: base pointers a0/a1 (ks=0/1) and b0/b1 carry all
// per-thread variability; unroll indices are immediate offsets.
#define LDA_(qm) do {                                                          \
    _Pragma("unroll") for (int m = 0; m < 4; ++m) {                            \
        Af[m][0] = *(const bf16x8*)(a0 + ((qm)*8192 + m*2048));                \
        Af[m][1] = *(const bf16x8*)(a1 + ((qm)*8192 + m*2048));                \
    }                                                                          \
} while (0)

#define LDB_(qn, Bf) do {                                                      \
    _Pragma("unroll") for (int n = 0; n < 2; ++n) {                            \
        Bf[n][0] = *(const bf16x8*)(b0 + ((qn)*4096 + n*2048));                \
        Bf[n][1] = *(const bf16x8*)(b1 + ((qn)*4096 + n*2048));                \
    }                                                                          \
} while (0)

#define MFMA_(qm, qn, Bf) do {                                                 \
    _Pragma("unroll") for (int m = 0; m < 4; ++m)                              \
    _Pragma("unroll") for (int n = 0; n < 2; ++n)                              \
    _Pragma("unroll") for (int ks = 0; ks < 2; ++ks)                           \
        acc[(qm)*4+m][(qn)*2+n] = __builtin_amdgcn_mfma_f32_16x16x32_bf16(     \
            Af[m][ks], Bf[n][ks], acc[(qm)*4+m][(qn)*2+n], 0, 0, 0);           \
} while (0)

// stage one 256x64 tile (4 x gload_lds16 per thread) from base gsrc (+koff)
// into LDS parity base ldst; j-strides are constants.
#define STAGE_(gsrc, koff, ldst) do {                                          \
    const uint8_t* _p = (gsrc) + (koff);                                       \
    _Pragma("unroll") for (int j = 0; j < 4; ++j)                              \
        gload_lds16(_p + (size_t)j * 64 * KB2, (ldst) + (sdst + j*8192));      \
} while (0)

__global__ __launch_bounds__(512, 2)
void gemm256_8ph(const unsigned short* __restrict__ A,
                 const unsigned short* __restrict__ Bw,
                 const float* __restrict__ invp,
                 const float* __restrict__ bias,
                 float* __restrict__ C, int M, int N, int K) {
    __shared__ unsigned short lds[2][2][GBM * GBK];   // 128 KiB
    char* ldsb = (char*)&lds[0][0][0];

    const size_t KB2 = (size_t)K * 2;     // bytes per logical row
    const int KT = K / GBK;

    // bijective XCD swizzle (grid % 8 == 0 guaranteed by dispatch guard)
    const int nwg = gridDim.x;
    const int b   = blockIdx.x;
    const int wg  = (b & 7) * (nwg >> 3) + (b >> 3);
    const int MT  = M / GBM;
    const int tm  = wg % MT;
    const int tn  = wg / MT;

    const int t     = threadIdx.x;
    const int lane  = t & 63;
    const int wid   = t >> 6;       // 0..7
    const int wm    = wid >> 2;     // 0..1
    const int wn    = wid & 3;      // 0..3
    const int laneQ = lane & 15;
    const int laneH = lane >> 4;
    const int xorv  = (laneQ & 7) << 4;     // T2 read swizzle
    const int lrow  = lane >> 3;            // staging row-within-8
    const int lcb   = (lane & 7) ^ lrow;    // inverse-swizzled source block

    // ---- precomputed 32-bit LDS read offsets (exact expansion of r5 map) ----
    const int col0  = (0   + laneH * 16) ^ xorv;
    const int col1  = (64  + laneH * 16) ^ xorv;
    const int aoff0 = wm * 16384 + laneQ * 128 + col0;
    const int aoff1 = wm * 16384 + laneQ * 128 + col1;
    const int boff0 = wn * 8192  + laneQ * 128 + col0;
    const int boff1 = wn * 8192  + laneQ * 128 + col1;
    const int sdst  = wid * 1024 + lane * 16;        // staging dest offset

    // ---- global staging base pointers (one per tensor) ----
    const uint8_t* gA = (const uint8_t*)A +
        ((size_t)tm * GBM + wid * 8 + lrow) * KB2 + (size_t)lcb * 16;
    const uint8_t* gB = (const uint8_t*)Bw +
        ((size_t)tn * GBN + wid * 8 + lrow) * KB2 + (size_t)lcb * 16;

    f32x4 acc[8][4] = {};
    bf16x8 Af[4][2], B0[2][2], B1[2][2];

    // ---- prologue: stage tiles 0 (parity 0) and 1 (parity 1) ----
    STAGE_(gB, (size_t)0,   ldsb + 32768);
    STAGE_(gA, (size_t)0,   ldsb);
    STAGE_(gB, (size_t)128, ldsb + 65536 + 32768);
    STAGE_(gA, (size_t)128, ldsb + 65536);
    asm volatile("s_waitcnt vmcnt(8)" ::: "memory");   // tile 0 landed
    __builtin_amdgcn_s_barrier();

    for (int kt = 0; kt < KT; ++kt) {
        const int coff = (kt & 1) << 16;          // 0 / 65536
        const char* ldsA = ldsb + coff;
        const char* ldsB = ldsb + coff + 32768;
        const char* a0 = ldsA + aoff0;
        const char* a1 = ldsA + aoff1;
        const char* b0 = ldsB + boff0;
        const char* b1 = ldsB + boff1;
        char* ldsAw = (char*)ldsA;                // kt+2 shares parity with kt
        char* ldsBw = (char*)ldsB;
        const bool more = (kt + 2) < KT;
        const size_t kb2 = (size_t)(kt + 2) * 128;

        // ---- P1: A(qm0)+B(qn0) reads; MFMA (0,0) ----
        LDA_(0);
        LDB_(0, B0);
        PH_IN();  MFMA_(0, 0, B0);  PH_OUT();

        // ---- P2: B(qn1) reads; MFMA (0,1) ----
        LDB_(1, B1);
        PH_IN();  MFMA_(0, 1, B1);  PH_OUT();

        // ---- P3: A(qm1) reads; stage B(kt+2) (B dead since P2-out); MFMA (1,1) ----
        LDA_(1);
        if (more) STAGE_(gB, kb2, ldsBw);
        PH_IN();  MFMA_(1, 1, B1);  PH_OUT();

        // ---- P4: stage A(kt+2) (A dead since P3-out); MFMA (1,0) from regs ----
        if (more) STAGE_(gA, kb2, ldsAw);
        __builtin_amdgcn_s_setprio(1);
        MFMA_(1, 0, B0);
        __builtin_amdgcn_s_setprio(0);
        if (more) asm volatile("s_waitcnt vmcnt(8)" ::: "memory"); // kt+1 landed
        else      asm volatile("s_waitcnt vmcnt(0)" ::: "memory"); // drain
        __builtin_amdgcn_s_barrier();
    }

    // ---- epilogue: C/D layout col=laneQ, row=laneH*4+reg [m89-verified] ----
    const float inv = *invp;
    float bv[4];
    #pragma unroll
    for (int n = 0; n < 4; ++n)
        bv[n] = bias[tn * GBN + wn * 64 + n * 16 + laneQ];

    #pragma unroll
    for (int m = 0; m < 8; ++m) {
        int rowb = tm * GBM + wm * 128 + m * 16 + laneH * 4;
        #pragma unroll
        for (int j = 0; j < 4; ++j) {
            float* cp = C + (size_t)(rowb + j) * N + tn * GBN + wn * 64;
            #pragma unroll
            for (int n = 0; n < 4; ++n)
                cp[n * 16 + laneQ] = acc[m][n][j] * inv + bv[n];
        }
    }
}

// ---------- fallback (insurance, mode-aware) ----------
__global__ void naive_kernel(const float* __restrict__ x,
                             const void* __restrict__ wsrc,
                             const uint32_t* flag,
                             const float* __restrict__ invp,
                             const float* __restrict__ bias,
                             float* __restrict__ out, int M, int N, int K) {
    const uint32_t mode = flag ? *flag : 0u;
    size_t idx = (size_t)blockIdx.x * blockDim.x + threadIdx.x;
    if (idx >= (size_t)M * N) return;
    int m = (int)(idx / N), n = (int)(idx % N);
    const float* xr = x + (size_t)m * K;
    float s = 0.f;
    if (mode == 0) {
        const float* wr = (const float*)wsrc + (size_t)n * K;
        for (int k = 0; k < K; ++k) s += xr[k] * wr[k];
    } else if (mode == 1) {
        const unsigned short* wr = (const unsigned short*)wsrc + (size_t)n * K;
        for (int k = 0; k < K; ++k)
            s += xr[k] * __uint_as_float(((uint32_t)wr[k]) << 16);
    } else {
        const uint8_t* wr = (const uint8_t*)wsrc + (size_t)n * K;
        for (int k = 0; k < K; ++k) s += xr[k] * fp8e4m3_to_f32(wr[k]);
    }
    out[idx] = s * (*invp) + bias[n];
}

extern "C" void kernel_launch(void* const* d_in, const int* in_sizes, int n_in,
                              void* d_out, int out_size, void* d_ws, size_t ws_size,
                              hipStream_t stream) {
    const float*    x    = (const float*)d_in[0];
    const void*     wsrc = d_in[1];
    const float*    inv  = (const float*)d_in[2];
    const float*    bias = (const float*)d_in[3];
    float*          out  = (float*)d_out;

    const int K = in_sizes[1] / in_sizes[3];   // D_IN  = 4096
    const int N = in_sizes[3];                 // D_OUT = 4096
    const int M = in_sizes[0] / K;             // B*S   = 8192

    const size_t needA = (size_t)M * K * sizeof(unsigned short);
    const size_t needB = (size_t)N * K * sizeof(unsigned short);

    const bool shape_ok = (M % GBM) == 0 && (N % GBN) == 0 && (K % GBK) == 0 &&
                          (K / GBK) >= 2 &&
                          (((M / GBM) * (N / GBN)) % 8) == 0;

    if (ws_size < needA + needB + 256 || !shape_ok) {
        size_t total = (size_t)M * N;
        uint32_t* flag = (ws_size >= 256) ? (uint32_t*)d_ws : nullptr;
        if (flag) detect_kernel<<<1, 256, 0, stream>>>((const uint32_t*)wsrc, flag);
        naive_kernel<<<(unsigned)((total + 255) / 256), 256, 0, stream>>>(
            x, wsrc, flag, inv, bias, out, M, N, K);
        return;
    }

    uint32_t*       flag = (uint32_t*)d_ws;
    unsigned short* Abf  = (unsigned short*)((char*)d_ws + 256);
    unsigned short* Wbf  = (unsigned short*)((char*)d_ws + 256 + needA);

    detect_kernel<<<1, 256, 0, stream>>>((const uint32_t*)wsrc, flag);
    cvt_x_kernel<<<2048, 256, 0, stream>>>(x, Abf, (size_t)M * K / 8);
    prep_w_kernel<<<2048, 256, 0, stream>>>(wsrc, flag, Wbf, (size_t)N * K / 8);

    dim3 grid((M / GBM) * (N / GBN));
    gemm256_8ph<<<grid, 512, 0, stream>>>(Abf, Wbf, inv, bias, out, M, N, K);
}